// Round 7
// baseline (143.441 us; speedup 1.0000x reference)
//
#include <hip/hip_runtime.h>
#include <hip/hip_bf16.h>

// CorrelationNetwork fused kernels for MI355X (gfx950) — round 7.
// R6 post-mortem: corr's LDS pipe was dominated by re-reading W2s frags
// every tile (128/264 LDS instrs per tile) + 2 barrier drains/tile.
// R7: W2 A-frags hoisted to 64 VGPRs ONCE per block (global gather,
// amortized); 256-thr blocks on 64-row tiles (acc=32 VGPR, peak ~115 <=
// 128 cap — R5's spill cliff respected); ping-pong At (2x16KB) + deferred
// store -> 1 barrier/tile; b2/w3 via t-dependent dup table (anti-LICM,
// stays transient); 1024 blocks = exactly 4/CU, no tail.

typedef __bf16 bf16x8 __attribute__((ext_vector_type(8)));
typedef float f32x4 __attribute__((ext_vector_type(4)));
typedef float f32x2 __attribute__((ext_vector_type(2)));

#define B_SZ 128
#define N_SZ 64
#define H_SZ 128

union Frag16 {
  uint4 q;
  __hip_bfloat162 h[4];
};

// ---- setup: 0..2047 prepass (4 bn-rows each), 2048..2111 W2->W2T bf16,
//      2112 softmax(mixing_weights), 2113 b2/w3 duplicated table
__global__ __launch_bounds__(256) void setup_kernel(
    const float* __restrict__ af, const float* __restrict__ W1,
    const float* __restrict__ b1, const float* __restrict__ W2,
    const float* __restrict__ mw, const float* __restrict__ b2,
    const float* __restrict__ w3, float* __restrict__ AiP,
    float* __restrict__ Aj, unsigned short* __restrict__ W2T,
    float* __restrict__ tab, float* __restrict__ outw)
{
  const int blk = blockIdx.x;
  const int tid = threadIdx.x;

  if (blk < 2048) {
    // prepass: AiP[bn,h] = sum_f f[bn,f]*W1[f,h] + b1[h]; Aj via W1[64+f]
    __shared__ float fl[4 * 64];
    const int bn0 = blk << 2;
    fl[tid] = af[((bn0 + (tid >> 6)) << 7) + (tid & 63)];
    __syncthreads();
    const int h    = tid & 127;
    const int half = tid >> 7;                 // 0 -> Ai, 1 -> Aj
    const float* Wp = W1 + ((half << 6) << 7) + h;
    float acc0 = 0.f, acc1 = 0.f, acc2 = 0.f, acc3 = 0.f;
#pragma unroll
    for (int fq = 0; fq < 16; ++fq) {
      const float w0 = Wp[(fq * 4 + 0) << 7];
      const float w1v = Wp[(fq * 4 + 1) << 7];
      const float w2v = Wp[(fq * 4 + 2) << 7];
      const float w3v = Wp[(fq * 4 + 3) << 7];
      const float4 f0 = *(const float4*)&fl[0 * 64 + (fq << 2)];
      const float4 f1 = *(const float4*)&fl[1 * 64 + (fq << 2)];
      const float4 f2 = *(const float4*)&fl[2 * 64 + (fq << 2)];
      const float4 f3 = *(const float4*)&fl[3 * 64 + (fq << 2)];
      acc0 = fmaf(f0.x, w0, fmaf(f0.y, w1v, fmaf(f0.z, w2v, fmaf(f0.w, w3v, acc0))));
      acc1 = fmaf(f1.x, w0, fmaf(f1.y, w1v, fmaf(f1.z, w2v, fmaf(f1.w, w3v, acc1))));
      acc2 = fmaf(f2.x, w0, fmaf(f2.y, w1v, fmaf(f2.z, w2v, fmaf(f2.w, w3v, acc2))));
      acc3 = fmaf(f3.x, w0, fmaf(f3.y, w1v, fmaf(f3.z, w2v, fmaf(f3.w, w3v, acc3))));
    }
    if (half == 0) {
      const float bb = b1[h];
      AiP[((bn0 + 0) << 7) + h] = acc0 + bb;
      AiP[((bn0 + 1) << 7) + h] = acc1 + bb;
      AiP[((bn0 + 2) << 7) + h] = acc2 + bb;
      AiP[((bn0 + 3) << 7) + h] = acc3 + bb;
    } else {
      Aj[((bn0 + 0) << 7) + h] = acc0;
      Aj[((bn0 + 1) << 7) + h] = acc1;
      Aj[((bn0 + 2) << 7) + h] = acc2;
      Aj[((bn0 + 3) << 7) + h] = acc3;
    }
  } else if (blk < 2112) {
    // W2 (128x128, k-major) -> W2T (n-major) bf16
    int idx = ((blk - 2048) << 8) + tid;       // 0..16383
    int k = idx >> 7, n = idx & 127;
    unsigned u = __float_as_uint(W2[idx]);
    u += 0x7fffu + ((u >> 16) & 1u);
    W2T[(n << 7) + k] = (unsigned short)(u >> 16);
  } else if (blk == 2112) {
    // softmax over 64 mixing weights
    if (tid < 64) {
      float v = mw[tid];
      float m = v;
      for (int off = 32; off > 0; off >>= 1) m = fmaxf(m, __shfl_xor(m, off));
      float e = expf(v - m);
      float s = e;
      for (int off = 32; off > 0; off >>= 1) s += __shfl_xor(s, off);
      outw[tid] = e / s;
    }
  } else {
    // tab: [b2 128][w3 128] duplicated at +256 (anti-LICM per-tile loads)
    const float v = (tid < 128) ? b2[tid] : w3[tid - 128];
    tab[tid] = v;
    tab[tid + 256] = v;
  }
}

// ---- main kernel: 1024 blocks x 256 thr (4 blocks/CU, exact fill).
// Block = (b, 8 i's). Tile = (b,i): 64 rows j x 128 w2cols, K=128.
// Waves: wm = wave&1 (64-col half, tm=4), wn = wave>>1 (32-row half, tn=2).
// MFMA swapped roles: D = W2frag(A) * h1frag(B) -> D[m=w2col][n=j-row].
// W2 frags in registers (gathered once); h1 tile ping-pongs in LDS;
// 1 barrier/tile with deferred sigmoid-store.
__global__ __launch_bounds__(256, 4) void corr_kernel(
    const float* __restrict__ AiP, const float* __restrict__ Aj,
    const unsigned short* __restrict__ W2T, const float* __restrict__ tab,
    const float* __restrict__ b3, float* __restrict__ out)
{
  __shared__ __align__(16) unsigned short S[2][64 * 128];  // 2 x 16 KB
  __shared__ float part[2][128];                           // [buf][row*2+wm]

  const int tid  = threadIdx.x;
  const int lane = tid & 63;
  const int wave = tid >> 6;            // 0..3
  const int c = lane & 15, g = lane >> 4;
  const int wm = wave & 1;              // w2col half
  const int wn = wave >> 1;             // row half (32 rows)

  const int b  = blockIdx.x >> 3;       // 0..127
  const int i0 = (blockIdx.x & 7) << 3; // this block's 8 i's

  // ---- one-time W2 A-frag gather from global W2T (L2-hot, amortized)
  bf16x8 wv[4][4];                      // [tm][kt], 64 VGPRs
#pragma unroll
  for (int tm = 0; tm < 4; ++tm)
#pragma unroll
    for (int kt = 0; kt < 4; ++kt)
      wv[tm][kt] = *(const bf16x8*)&W2T[(((wm << 6) + (tm << 4) + c) << 7) +
                                        (((kt << 2) + g) << 3)];

  const float* AjB = Aj + ((b << 6) << 7);
  const int kq8 = tid & 15;             // 16B k-chunk
  const int rr  = tid >> 4;             // 0..15 (row within pass)
  const float bias3 = b3[0];
  const f32x4 zero4 = {0.f, 0.f, 0.f, 0.f};
  const f32x2 zero2 = {0.f, 0.f};

  // ---- build tile 0 into S[0]
  {
    const float* AiB = AiP + (((b << 6) + i0) << 7) + (kq8 << 3);
    const f32x4 a0 = *(const f32x4*)AiB;
    const f32x4 a1 = *(const f32x4*)(AiB + 4);
#pragma unroll
    for (int pass = 0; pass < 4; ++pass) {
      const int r = (pass << 4) + rr;
      const float* jr = AjB + (r << 7) + (kq8 << 3);
      const f32x4 j0 = *(const f32x4*)jr;
      const f32x4 j1 = *(const f32x4*)(jr + 4);
      const f32x4 s0 = __builtin_elementwise_max(a0 + j0, zero4);
      const f32x4 s1 = __builtin_elementwise_max(a1 + j1, zero4);
      Frag16 u;
      u.h[0] = __float22bfloat162_rn(float2{s0.x, s0.y});
      u.h[1] = __float22bfloat162_rn(float2{s0.z, s0.w});
      u.h[2] = __float22bfloat162_rn(float2{s1.x, s1.y});
      u.h[3] = __float22bfloat162_rn(float2{s1.z, s1.w});
      *(uint4*)&S[0][(r << 7) + ((kq8 ^ rr) << 3)] = u.q;
    }
  }
  __syncthreads();

#pragma unroll 1
  for (int t = 0; t < 8; ++t) {
    const unsigned short* At = S[t & 1];
    const float* tb = tab + ((t & 1) << 8);   // t-dependent -> no LICM hoist

    // acc init = b2 (D = A*B + C)
    f32x4 acc[4][2];
#pragma unroll
    for (int tm = 0; tm < 4; ++tm) {
      const f32x4 b2q = *(const f32x4*)(tb + (wm << 6) + (tm << 4) + (g << 2));
      acc[tm][0] = b2q;
      acc[tm][1] = b2q;
    }

#pragma unroll
    for (int kt = 0; kt < 4; ++kt) {
      const int es = ((kt << 2) + g) ^ c;     // swizzled chunk (row low4 == c)
      bf16x8 hv[2];
#pragma unroll
      for (int tn = 0; tn < 2; ++tn)
        hv[tn] = *(const bf16x8*)&At[(((wn << 5) + (tn << 4) + c) << 7) +
                                     (es << 3)];
#pragma unroll
      for (int tm = 0; tm < 4; ++tm) {
        acc[tm][0] = __builtin_amdgcn_mfma_f32_16x16x32_bf16(
            wv[tm][kt], hv[0], acc[tm][0], 0, 0, 0);
        acc[tm][1] = __builtin_amdgcn_mfma_f32_16x16x32_bf16(
            wv[tm][kt], hv[1], acc[tm][1], 0, 0, 0);
      }
    }

    // ---- epilogue: in-lane over (tm,p), shfl over g, part combine over wm
    f32x2 sp0 = zero2, sp1 = zero2;
#pragma unroll
    for (int tm = 0; tm < 4; ++tm) {
      const f32x4 w3q =
          *(const f32x4*)(tb + 128 + (wm << 6) + (tm << 4) + (g << 2));
      sp0 = __builtin_elementwise_max(acc[tm][0].xy, zero2) * w3q.xy + sp0;
      sp0 = __builtin_elementwise_max(acc[tm][0].zw, zero2) * w3q.zw + sp0;
      sp1 = __builtin_elementwise_max(acc[tm][1].xy, zero2) * w3q.xy + sp1;
      sp1 = __builtin_elementwise_max(acc[tm][1].zw, zero2) * w3q.zw + sp1;
    }
    float s0 = sp0.x + sp0.y;
    float s1 = sp1.x + sp1.y;
    s0 += __shfl_xor(s0, 16);
    s0 += __shfl_xor(s0, 32);
    s1 += __shfl_xor(s1, 16);
    s1 += __shfl_xor(s1, 32);
    if (g == 0) {                              // rows wn*32+{0,16}+c
      part[t & 1][(((wn << 5) + c) << 1) + wm]      = s0;
      part[t & 1][(((wn << 5) + 16 + c) << 1) + wm] = s1;
    }

    // ---- build tile t+1 into the other buffer (overlaps MFMA issue)
    if (t < 7) {
      const float* AiB = AiP + (((b << 6) + i0 + t + 1) << 7) + (kq8 << 3);
      const f32x4 a0 = *(const f32x4*)AiB;
      const f32x4 a1 = *(const f32x4*)(AiB + 4);
      unsigned short* Sn = S[(t + 1) & 1];
#pragma unroll
      for (int pass = 0; pass < 4; ++pass) {
        const int r = (pass << 4) + rr;
        const float* jr = AjB + (r << 7) + (kq8 << 3);
        const f32x4 j0 = *(const f32x4*)jr;
        const f32x4 j1 = *(const f32x4*)(jr + 4);
        const f32x4 q0 = __builtin_elementwise_max(a0 + j0, zero4);
        const f32x4 q1 = __builtin_elementwise_max(a1 + j1, zero4);
        Frag16 u;
        u.h[0] = __float22bfloat162_rn(float2{q0.x, q0.y});
        u.h[1] = __float22bfloat162_rn(float2{q0.z, q0.w});
        u.h[2] = __float22bfloat162_rn(float2{q1.x, q1.y});
        u.h[3] = __float22bfloat162_rn(float2{q1.z, q1.w});
        *(uint4*)&Sn[(r << 7) + ((kq8 ^ rr) << 3)] = u.q;
      }
    }

    __syncthreads();   // the only barrier per tile

    // ---- deferred store of tile t (part[t&1] now visible)
    if (tid < 64) {
      const float2 pp = *(const float2*)&part[t & 1][tid << 1];
      const float v = pp.x + pp.y + bias3;
      out[(b << 12) + ((i0 + t) << 6) + tid] = 1.f / (1.f + __expf(-v));
    }
  }
}

extern "C" void kernel_launch(void* const* d_in, const int* in_sizes, int n_in,
                              void* d_out, int out_size, void* d_ws,
                              size_t ws_size, hipStream_t stream)
{
  const float* af = (const float*)d_in[0];   // (128,64,128)
  const float* W1 = (const float*)d_in[1];   // (128,128)
  const float* b1 = (const float*)d_in[2];   // (128,)
  const float* W2 = (const float*)d_in[3];   // (128,128)
  const float* b2 = (const float*)d_in[4];   // (128,)
  const float* w3 = (const float*)d_in[5];   // (128,)
  const float* b3 = (const float*)d_in[6];   // (1,)
  const float* mw = (const float*)d_in[7];   // (64,)
  float* out = (float*)d_out;                // 524288 corr + 64 weights

  float* AiP = (float*)d_ws;                           // 4 MB
  float* Aj  = AiP + B_SZ * N_SZ * H_SZ;               // 4 MB
  unsigned short* W2T = (unsigned short*)(Aj + B_SZ * N_SZ * H_SZ);  // 32 KB
  float* tab = (float*)(W2T + H_SZ * H_SZ);            // 2 KB

  setup_kernel<<<2114, 256, 0, stream>>>(af, W1, b1, W2, mw, b2, w3,
                                         AiP, Aj, W2T, tab,
                                         out + B_SZ * N_SZ * N_SZ);
  // 1024 blocks x 256 thr = exactly 4 blocks/CU; block = (b, 8 i's)
  corr_kernel<<<1024, 256, 0, stream>>>(AiP, Aj, W2T, tab, b3, out);
}

// Round 8
// 113.205 us; speedup vs baseline: 1.2671x; 1.2671x over previous
//
#include <hip/hip_runtime.h>
#include <hip/hip_bf16.h>

// CorrelationNetwork fused kernels for MI355X (gfx950) — round 8.
// R7 post-mortem: structure sound, but the compiler allocated only 64 VGPR
// (occupancy-first heuristic; launch_bounds min-waves doesn't force spend)
// and spilled the held W2 fragments -> 200 MB scratch FETCH, 70 us.
// R8 = R7 + amdgpu_waves_per_eu(2,2): pins 2 waves/EU -> 256-VGPR budget;
// wv(64)+acc(32)+temps ~140 fits with margin. Everything else unchanged:
// W2 A-frags gathered to regs once per block; 64-row tiles; ping-pong At
// (2x16KB) + deferred store -> 1 barrier/tile; swapped-role MFMA.

typedef __bf16 bf16x8 __attribute__((ext_vector_type(8)));
typedef float f32x4 __attribute__((ext_vector_type(4)));
typedef float f32x2 __attribute__((ext_vector_type(2)));

#define B_SZ 128
#define N_SZ 64
#define H_SZ 128

union Frag16 {
  uint4 q;
  __hip_bfloat162 h[4];
};

// ---- setup: 0..2047 prepass (4 bn-rows each), 2048..2111 W2->W2T bf16,
//      2112 softmax(mixing_weights), 2113 b2/w3 duplicated table
__global__ __launch_bounds__(256) void setup_kernel(
    const float* __restrict__ af, const float* __restrict__ W1,
    const float* __restrict__ b1, const float* __restrict__ W2,
    const float* __restrict__ mw, const float* __restrict__ b2,
    const float* __restrict__ w3, float* __restrict__ AiP,
    float* __restrict__ Aj, unsigned short* __restrict__ W2T,
    float* __restrict__ tab, float* __restrict__ outw)
{
  const int blk = blockIdx.x;
  const int tid = threadIdx.x;

  if (blk < 2048) {
    // prepass: AiP[bn,h] = sum_f f[bn,f]*W1[f,h] + b1[h]; Aj via W1[64+f]
    __shared__ float fl[4 * 64];
    const int bn0 = blk << 2;
    fl[tid] = af[((bn0 + (tid >> 6)) << 7) + (tid & 63)];
    __syncthreads();
    const int h    = tid & 127;
    const int half = tid >> 7;                 // 0 -> Ai, 1 -> Aj
    const float* Wp = W1 + ((half << 6) << 7) + h;
    float acc0 = 0.f, acc1 = 0.f, acc2 = 0.f, acc3 = 0.f;
#pragma unroll
    for (int fq = 0; fq < 16; ++fq) {
      const float w0 = Wp[(fq * 4 + 0) << 7];
      const float w1v = Wp[(fq * 4 + 1) << 7];
      const float w2v = Wp[(fq * 4 + 2) << 7];
      const float w3v = Wp[(fq * 4 + 3) << 7];
      const float4 f0 = *(const float4*)&fl[0 * 64 + (fq << 2)];
      const float4 f1 = *(const float4*)&fl[1 * 64 + (fq << 2)];
      const float4 f2 = *(const float4*)&fl[2 * 64 + (fq << 2)];
      const float4 f3 = *(const float4*)&fl[3 * 64 + (fq << 2)];
      acc0 = fmaf(f0.x, w0, fmaf(f0.y, w1v, fmaf(f0.z, w2v, fmaf(f0.w, w3v, acc0))));
      acc1 = fmaf(f1.x, w0, fmaf(f1.y, w1v, fmaf(f1.z, w2v, fmaf(f1.w, w3v, acc1))));
      acc2 = fmaf(f2.x, w0, fmaf(f2.y, w1v, fmaf(f2.z, w2v, fmaf(f2.w, w3v, acc2))));
      acc3 = fmaf(f3.x, w0, fmaf(f3.y, w1v, fmaf(f3.z, w2v, fmaf(f3.w, w3v, acc3))));
    }
    if (half == 0) {
      const float bb = b1[h];
      AiP[((bn0 + 0) << 7) + h] = acc0 + bb;
      AiP[((bn0 + 1) << 7) + h] = acc1 + bb;
      AiP[((bn0 + 2) << 7) + h] = acc2 + bb;
      AiP[((bn0 + 3) << 7) + h] = acc3 + bb;
    } else {
      Aj[((bn0 + 0) << 7) + h] = acc0;
      Aj[((bn0 + 1) << 7) + h] = acc1;
      Aj[((bn0 + 2) << 7) + h] = acc2;
      Aj[((bn0 + 3) << 7) + h] = acc3;
    }
  } else if (blk < 2112) {
    // W2 (128x128, k-major) -> W2T (n-major) bf16
    int idx = ((blk - 2048) << 8) + tid;       // 0..16383
    int k = idx >> 7, n = idx & 127;
    unsigned u = __float_as_uint(W2[idx]);
    u += 0x7fffu + ((u >> 16) & 1u);
    W2T[(n << 7) + k] = (unsigned short)(u >> 16);
  } else if (blk == 2112) {
    // softmax over 64 mixing weights
    if (tid < 64) {
      float v = mw[tid];
      float m = v;
      for (int off = 32; off > 0; off >>= 1) m = fmaxf(m, __shfl_xor(m, off));
      float e = expf(v - m);
      float s = e;
      for (int off = 32; off > 0; off >>= 1) s += __shfl_xor(s, off);
      outw[tid] = e / s;
    }
  } else {
    // tab: [b2 128][w3 128] duplicated at +256 (anti-LICM per-tile loads)
    const float v = (tid < 128) ? b2[tid] : w3[tid - 128];
    tab[tid] = v;
    tab[tid + 256] = v;
  }
}

// ---- main kernel: 1024 blocks x 256 thr. Block = (b, 8 i's).
// Tile = (b,i): 64 rows j x 128 w2cols, K=128.
// Waves: wm = wave&1 (64-col half, tm=4), wn = wave>>1 (32-row half, tn=2).
// MFMA swapped roles: D = W2frag(A) * h1frag(B) -> D[m=w2col][n=j-row].
// W2 frags in registers (gathered once, 64 VGPR held — waves_per_eu(2,2)
// gives the 256-reg budget so they actually STAY in registers);
// h1 tile ping-pongs in LDS; 1 barrier/tile with deferred sigmoid-store.
__global__ __launch_bounds__(256)
__attribute__((amdgpu_waves_per_eu(2, 2))) void corr_kernel(
    const float* __restrict__ AiP, const float* __restrict__ Aj,
    const unsigned short* __restrict__ W2T, const float* __restrict__ tab,
    const float* __restrict__ b3, float* __restrict__ out)
{
  __shared__ __align__(16) unsigned short S[2][64 * 128];  // 2 x 16 KB
  __shared__ float part[2][128];                           // [buf][row*2+wm]

  const int tid  = threadIdx.x;
  const int lane = tid & 63;
  const int wave = tid >> 6;            // 0..3
  const int c = lane & 15, g = lane >> 4;
  const int wm = wave & 1;              // w2col half
  const int wn = wave >> 1;             // row half (32 rows)

  const int b  = blockIdx.x >> 3;       // 0..127
  const int i0 = (blockIdx.x & 7) << 3; // this block's 8 i's

  // ---- one-time W2 A-frag gather from global W2T (L2-hot, amortized)
  bf16x8 wv[4][4];                      // [tm][kt], 64 VGPRs HELD
#pragma unroll
  for (int tm = 0; tm < 4; ++tm)
#pragma unroll
    for (int kt = 0; kt < 4; ++kt)
      wv[tm][kt] = *(const bf16x8*)&W2T[(((wm << 6) + (tm << 4) + c) << 7) +
                                        (((kt << 2) + g) << 3)];

  const float* AjB = Aj + ((b << 6) << 7);
  const int kq8 = tid & 15;             // 16B k-chunk
  const int rr  = tid >> 4;             // 0..15 (row within pass)
  const float bias3 = b3[0];
  const f32x4 zero4 = {0.f, 0.f, 0.f, 0.f};
  const f32x2 zero2 = {0.f, 0.f};

  // ---- build tile 0 into S[0]
  {
    const float* AiB = AiP + (((b << 6) + i0) << 7) + (kq8 << 3);
    const f32x4 a0 = *(const f32x4*)AiB;
    const f32x4 a1 = *(const f32x4*)(AiB + 4);
#pragma unroll
    for (int pass = 0; pass < 4; ++pass) {
      const int r = (pass << 4) + rr;
      const float* jr = AjB + (r << 7) + (kq8 << 3);
      const f32x4 j0 = *(const f32x4*)jr;
      const f32x4 j1 = *(const f32x4*)(jr + 4);
      const f32x4 s0 = __builtin_elementwise_max(a0 + j0, zero4);
      const f32x4 s1 = __builtin_elementwise_max(a1 + j1, zero4);
      Frag16 u;
      u.h[0] = __float22bfloat162_rn(float2{s0.x, s0.y});
      u.h[1] = __float22bfloat162_rn(float2{s0.z, s0.w});
      u.h[2] = __float22bfloat162_rn(float2{s1.x, s1.y});
      u.h[3] = __float22bfloat162_rn(float2{s1.z, s1.w});
      *(uint4*)&S[0][(r << 7) + ((kq8 ^ rr) << 3)] = u.q;
    }
  }
  __syncthreads();

#pragma unroll 1
  for (int t = 0; t < 8; ++t) {
    const unsigned short* At = S[t & 1];
    const float* tb = tab + ((t & 1) << 8);   // t-dependent -> no LICM hoist

    // acc init = b2 (D = A*B + C)
    f32x4 acc[4][2];
#pragma unroll
    for (int tm = 0; tm < 4; ++tm) {
      const f32x4 b2q = *(const f32x4*)(tb + (wm << 6) + (tm << 4) + (g << 2));
      acc[tm][0] = b2q;
      acc[tm][1] = b2q;
    }

#pragma unroll
    for (int kt = 0; kt < 4; ++kt) {
      const int es = ((kt << 2) + g) ^ c;     // swizzled chunk (row low4 == c)
      bf16x8 hv[2];
#pragma unroll
      for (int tn = 0; tn < 2; ++tn)
        hv[tn] = *(const bf16x8*)&At[(((wn << 5) + (tn << 4) + c) << 7) +
                                     (es << 3)];
#pragma unroll
      for (int tm = 0; tm < 4; ++tm) {
        acc[tm][0] = __builtin_amdgcn_mfma_f32_16x16x32_bf16(
            wv[tm][kt], hv[0], acc[tm][0], 0, 0, 0);
        acc[tm][1] = __builtin_amdgcn_mfma_f32_16x16x32_bf16(
            wv[tm][kt], hv[1], acc[tm][1], 0, 0, 0);
      }
    }

    // ---- epilogue: in-lane over (tm,p), shfl over g, part combine over wm
    f32x2 sp0 = zero2, sp1 = zero2;
#pragma unroll
    for (int tm = 0; tm < 4; ++tm) {
      const f32x4 w3q =
          *(const f32x4*)(tb + 128 + (wm << 6) + (tm << 4) + (g << 2));
      sp0 = __builtin_elementwise_max(acc[tm][0].xy, zero2) * w3q.xy + sp0;
      sp0 = __builtin_elementwise_max(acc[tm][0].zw, zero2) * w3q.zw + sp0;
      sp1 = __builtin_elementwise_max(acc[tm][1].xy, zero2) * w3q.xy + sp1;
      sp1 = __builtin_elementwise_max(acc[tm][1].zw, zero2) * w3q.zw + sp1;
    }
    float s0 = sp0.x + sp0.y;
    float s1 = sp1.x + sp1.y;
    s0 += __shfl_xor(s0, 16);
    s0 += __shfl_xor(s0, 32);
    s1 += __shfl_xor(s1, 16);
    s1 += __shfl_xor(s1, 32);
    if (g == 0) {                              // rows wn*32+{0,16}+c
      part[t & 1][(((wn << 5) + c) << 1) + wm]      = s0;
      part[t & 1][(((wn << 5) + 16 + c) << 1) + wm] = s1;
    }

    // ---- build tile t+1 into the other buffer (overlaps MFMA issue)
    if (t < 7) {
      const float* AiB = AiP + (((b << 6) + i0 + t + 1) << 7) + (kq8 << 3);
      const f32x4 a0 = *(const f32x4*)AiB;
      const f32x4 a1 = *(const f32x4*)(AiB + 4);
      unsigned short* Sn = S[(t + 1) & 1];
#pragma unroll
      for (int pass = 0; pass < 4; ++pass) {
        const int r = (pass << 4) + rr;
        const float* jr = AjB + (r << 7) + (kq8 << 3);
        const f32x4 j0 = *(const f32x4*)jr;
        const f32x4 j1 = *(const f32x4*)(jr + 4);
        const f32x4 q0 = __builtin_elementwise_max(a0 + j0, zero4);
        const f32x4 q1 = __builtin_elementwise_max(a1 + j1, zero4);
        Frag16 u;
        u.h[0] = __float22bfloat162_rn(float2{q0.x, q0.y});
        u.h[1] = __float22bfloat162_rn(float2{q0.z, q0.w});
        u.h[2] = __float22bfloat162_rn(float2{q1.x, q1.y});
        u.h[3] = __float22bfloat162_rn(float2{q1.z, q1.w});
        *(uint4*)&Sn[(r << 7) + ((kq8 ^ rr) << 3)] = u.q;
      }
    }

    __syncthreads();   // the only barrier per tile

    // ---- deferred store of tile t (part[t&1] now visible)
    if (tid < 64) {
      const float2 pp = *(const float2*)&part[t & 1][tid << 1];
      const float v = pp.x + pp.y + bias3;
      out[(b << 12) + ((i0 + t) << 6) + tid] = 1.f / (1.f + __expf(-v));
    }
  }
}

extern "C" void kernel_launch(void* const* d_in, const int* in_sizes, int n_in,
                              void* d_out, int out_size, void* d_ws,
                              size_t ws_size, hipStream_t stream)
{
  const float* af = (const float*)d_in[0];   // (128,64,128)
  const float* W1 = (const float*)d_in[1];   // (128,128)
  const float* b1 = (const float*)d_in[2];   // (128,)
  const float* W2 = (const float*)d_in[3];   // (128,128)
  const float* b2 = (const float*)d_in[4];   // (128,)
  const float* w3 = (const float*)d_in[5];   // (128,)
  const float* b3 = (const float*)d_in[6];   // (1,)
  const float* mw = (const float*)d_in[7];   // (64,)
  float* out = (float*)d_out;                // 524288 corr + 64 weights

  float* AiP = (float*)d_ws;                           // 4 MB
  float* Aj  = AiP + B_SZ * N_SZ * H_SZ;               // 4 MB
  unsigned short* W2T = (unsigned short*)(Aj + B_SZ * N_SZ * H_SZ);  // 32 KB
  float* tab = (float*)(W2T + H_SZ * H_SZ);            // 2 KB

  setup_kernel<<<2114, 256, 0, stream>>>(af, W1, b1, W2, mw, b2, w3,
                                         AiP, Aj, W2T, tab,
                                         out + B_SZ * N_SZ * N_SZ);
  corr_kernel<<<1024, 256, 0, stream>>>(AiP, Aj, W2T, tab, b3, out);
}

// Round 9
// 109.907 us; speedup vs baseline: 1.3051x; 1.0300x over previous
//
#include <hip/hip_runtime.h>
#include <hip/hip_bf16.h>

// CorrelationNetwork fused kernels for MI355X (gfx950) — round 9.
// R8 post-mortem: no spill, but corr stayed 43.8us at 17% occupancy.
// Cross-round insight: R4/R6/R8 all land 35-44us because barrier-phased
// tiles serialize the pipes (all waves in the same phase; VALU+TA+LDS+MFMA
// sum instead of overlap). R9 = R5's barrier-free independent-wave strips,
// with the register budget actually sized to fit (R5's failure): per-wave
// peak ~160 regs under waves_per_eu(2,3) floor-256 budget. Stage W2^T +
// Aj once, ONE barrier, then 2 strips/wave of 32 rows x 128 cols, h1 built
// in regs from LDS, in-lane epilogue + 2 shfl + direct store. Anti-hoist:
// kt order XOR strip-index, b2/w3 via strip-indexed duplicate table.

typedef __bf16 bf16x8 __attribute__((ext_vector_type(8)));
typedef float f32x4 __attribute__((ext_vector_type(4)));
typedef float f32x2 __attribute__((ext_vector_type(2)));

#define B_SZ 128
#define N_SZ 64
#define H_SZ 128
#define AJ_STRIDE 132   // fp32 row stride: 132%32=4 -> uniform-bank b128 reads

union FragU {
  bf16x8 v;
  __hip_bfloat162 h[4];
};

// ---- setup: 0..2047 prepass (4 bn-rows each), 2048..2111 W2->W2T bf16,
//      2112 softmax(mixing_weights), 2113 b2/w3 duplicated table
__global__ __launch_bounds__(256) void setup_kernel(
    const float* __restrict__ af, const float* __restrict__ W1,
    const float* __restrict__ b1, const float* __restrict__ W2,
    const float* __restrict__ mw, const float* __restrict__ b2,
    const float* __restrict__ w3, float* __restrict__ AiP,
    float* __restrict__ Aj, unsigned short* __restrict__ W2T,
    float* __restrict__ tab, float* __restrict__ outw)
{
  const int blk = blockIdx.x;
  const int tid = threadIdx.x;

  if (blk < 2048) {
    // prepass: AiP[bn,h] = sum_f f[bn,f]*W1[f,h] + b1[h]; Aj via W1[64+f]
    __shared__ float fl[4 * 64];
    const int bn0 = blk << 2;
    fl[tid] = af[((bn0 + (tid >> 6)) << 7) + (tid & 63)];
    __syncthreads();
    const int h    = tid & 127;
    const int half = tid >> 7;                 // 0 -> Ai, 1 -> Aj
    const float* Wp = W1 + ((half << 6) << 7) + h;
    float acc0 = 0.f, acc1 = 0.f, acc2 = 0.f, acc3 = 0.f;
#pragma unroll
    for (int fq = 0; fq < 16; ++fq) {
      const float w0 = Wp[(fq * 4 + 0) << 7];
      const float w1v = Wp[(fq * 4 + 1) << 7];
      const float w2v = Wp[(fq * 4 + 2) << 7];
      const float w3v = Wp[(fq * 4 + 3) << 7];
      const float4 f0 = *(const float4*)&fl[0 * 64 + (fq << 2)];
      const float4 f1 = *(const float4*)&fl[1 * 64 + (fq << 2)];
      const float4 f2 = *(const float4*)&fl[2 * 64 + (fq << 2)];
      const float4 f3 = *(const float4*)&fl[3 * 64 + (fq << 2)];
      acc0 = fmaf(f0.x, w0, fmaf(f0.y, w1v, fmaf(f0.z, w2v, fmaf(f0.w, w3v, acc0))));
      acc1 = fmaf(f1.x, w0, fmaf(f1.y, w1v, fmaf(f1.z, w2v, fmaf(f1.w, w3v, acc1))));
      acc2 = fmaf(f2.x, w0, fmaf(f2.y, w1v, fmaf(f2.z, w2v, fmaf(f2.w, w3v, acc2))));
      acc3 = fmaf(f3.x, w0, fmaf(f3.y, w1v, fmaf(f3.z, w2v, fmaf(f3.w, w3v, acc3))));
    }
    if (half == 0) {
      const float bb = b1[h];
      AiP[((bn0 + 0) << 7) + h] = acc0 + bb;
      AiP[((bn0 + 1) << 7) + h] = acc1 + bb;
      AiP[((bn0 + 2) << 7) + h] = acc2 + bb;
      AiP[((bn0 + 3) << 7) + h] = acc3 + bb;
    } else {
      Aj[((bn0 + 0) << 7) + h] = acc0;
      Aj[((bn0 + 1) << 7) + h] = acc1;
      Aj[((bn0 + 2) << 7) + h] = acc2;
      Aj[((bn0 + 3) << 7) + h] = acc3;
    }
  } else if (blk < 2112) {
    // W2 (128x128, k-major) -> W2T (n-major) bf16
    int idx = ((blk - 2048) << 8) + tid;       // 0..16383
    int k = idx >> 7, n = idx & 127;
    unsigned u = __float_as_uint(W2[idx]);
    u += 0x7fffu + ((u >> 16) & 1u);
    W2T[(n << 7) + k] = (unsigned short)(u >> 16);
  } else if (blk == 2112) {
    // softmax over 64 mixing weights
    if (tid < 64) {
      float v = mw[tid];
      float m = v;
      for (int off = 32; off > 0; off >>= 1) m = fmaxf(m, __shfl_xor(m, off));
      float e = expf(v - m);
      float s = e;
      for (int off = 32; off > 0; off >>= 1) s += __shfl_xor(s, off);
      outw[tid] = e / s;
    }
  } else {
    // tab: [b2 128][w3 128] duplicated at +256 (anti-hoist per-strip loads)
    const float v = (tid < 128) ? b2[tid] : w3[tid - 128];
    tab[tid] = v;
    tab[tid + 256] = v;
  }
}

// ---- main kernel: 1024 blocks x 512 thr. Block = (b, 8 i's).
// Stage W2s (bf16 swizzled) + AjS (fp32, stride 132) once, ONE barrier,
// then 8 waves x 2 strips: strip = (i, jh): 32 rows j = jh*32..+31,
// all 128 w2cols, K=128. MFMA swapped roles: D = W2frag(A)*h1frag(B) ->
// D[m=w2col][n=j-row]; C layout m = 16tm+4g+p, n = c (verified R3-R8).
// No inter-wave coupling after the single barrier: pipes overlap across
// waves (m114) instead of phase-serializing.
__global__ __launch_bounds__(512)
__attribute__((amdgpu_waves_per_eu(2, 3))) void corr_kernel(
    const float* __restrict__ AiP, const float* __restrict__ Aj,
    const unsigned short* __restrict__ W2T, const float* __restrict__ tab,
    const float* __restrict__ b3, float* __restrict__ out)
{
  __shared__ __align__(16) unsigned short W2s[128 * 128];   // 32 KB
  __shared__ __align__(16) float AjS[64 * AJ_STRIDE];       // 33 KB

  const int tid  = threadIdx.x;
  const int lane = tid & 63;
  const int wave = tid >> 6;            // 0..7
  const int c = lane & 15, g = lane >> 4;

  const int b  = blockIdx.x >> 3;       // 0..127
  const int i0 = (blockIdx.x & 7) << 3; // this block's 8 i's

  // ---- stage W2T -> W2s (16B-chunk XOR swizzle), coalesced
  {
    const uint4* src = (const uint4*)W2T;     // 2048 x 16B chunks
#pragma unroll
    for (int it = 0; it < 4; ++it) {
      const int idx = (it << 9) + tid;
      const int n = idx >> 4, e = idx & 15;
      *(uint4*)&W2s[(n << 7) + ((e ^ (n & 15)) << 3)] = src[idx];
    }
  }
  // ---- stage this b's Aj (64 x 128 fp32) -> AjS, padded stride 132
  {
    const float4* src = (const float4*)(Aj + ((b << 6) << 7));  // 2048 f32x4
#pragma unroll
    for (int it = 0; it < 4; ++it) {
      const int idx = (it << 9) + tid;
      const int row = idx >> 5, c4 = idx & 31;
      *(float4*)&AjS[row * AJ_STRIDE + (c4 << 2)] = src[idx];
    }
  }
  __syncthreads();   // the ONLY barrier

  const float bias3 = b3[0];
  const f32x4 zero4 = {0.f, 0.f, 0.f, 0.f};
  const f32x2 zero2 = {0.f, 0.f};

#pragma unroll 1
  for (int si = 0; si < 2; ++si) {
    const int i  = i0 + (wave >> 1) + (si << 2);
    const int jh = wave & 1;
    const float* tb  = tab + (si << 8);       // strip-dep -> no hoist/hold
    const float* aip = AiP + (((b << 6) + i) << 7) + (g << 3);

    // acc init = b2 (D = A*B + C): acc[tm][*][p] = b2[16tm+4g+p]
    f32x4 acc[8][2];
#pragma unroll
    for (int tm = 0; tm < 8; ++tm) {
      const f32x4 b2q = *(const f32x4*)(tb + (tm << 4) + (g << 2));
      acc[tm][0] = b2q;
      acc[tm][1] = b2q;
    }

#pragma unroll
    for (int kt = 0; kt < 4; ++kt) {
      const int k = kt ^ si;                  // strip-dep k-order (anti-CSE)
      // Ai slice: 8 floats, broadcast across c-lanes (L1-resident)
      const f32x4 ai0 = *(const f32x4*)(aip + (k << 5));
      const f32x4 ai1 = *(const f32x4*)(aip + (k << 5) + 4);

      // build 2 h1 B-frags in regs: row = jh*32+16tn+c, k-slice = 32k+8g..+7
      FragU hv[2];
#pragma unroll
      for (int tn = 0; tn < 2; ++tn) {
        const float* ajp =
            &AjS[((jh << 5) + (tn << 4) + c) * AJ_STRIDE + (k << 5) + (g << 3)];
        const f32x4 aj0 = *(const f32x4*)ajp;
        const f32x4 aj1 = *(const f32x4*)(ajp + 4);
        const f32x4 s0 = __builtin_elementwise_max(ai0 + aj0, zero4);
        const f32x4 s1 = __builtin_elementwise_max(ai1 + aj1, zero4);
        hv[tn].h[0] = __float22bfloat162_rn(float2{s0.x, s0.y});
        hv[tn].h[1] = __float22bfloat162_rn(float2{s0.z, s0.w});
        hv[tn].h[2] = __float22bfloat162_rn(float2{s1.x, s1.y});
        hv[tn].h[3] = __float22bfloat162_rn(float2{s1.z, s1.w});
      }

      const int es = ((k << 2) + g) ^ c;      // W2s swizzled chunk
#pragma unroll
      for (int tm = 0; tm < 8; ++tm) {
        const bf16x8 wv =
            *(const bf16x8*)&W2s[(((tm << 4) + c) << 7) + (es << 3)];
        acc[tm][0] = __builtin_amdgcn_mfma_f32_16x16x32_bf16(
            wv, hv[0].v, acc[tm][0], 0, 0, 0);
        acc[tm][1] = __builtin_amdgcn_mfma_f32_16x16x32_bf16(
            wv, hv[1].v, acc[tm][1], 0, 0, 0);
      }
    }

    // ---- epilogue: in-lane over (tm,p), shfl over g (m bits 2..3), store
    f32x2 sp0 = zero2, sp1 = zero2;
#pragma unroll
    for (int tm = 0; tm < 8; ++tm) {
      const f32x4 w3q = *(const f32x4*)(tb + 128 + (tm << 4) + (g << 2));
      sp0 = __builtin_elementwise_max(acc[tm][0].xy, zero2) * w3q.xy + sp0;
      sp0 = __builtin_elementwise_max(acc[tm][0].zw, zero2) * w3q.zw + sp0;
      sp1 = __builtin_elementwise_max(acc[tm][1].xy, zero2) * w3q.xy + sp1;
      sp1 = __builtin_elementwise_max(acc[tm][1].zw, zero2) * w3q.zw + sp1;
    }
    float s0 = sp0.x + sp0.y;
    float s1 = sp1.x + sp1.y;
    s0 += __shfl_xor(s0, 16);
    s0 += __shfl_xor(s0, 32);
    s1 += __shfl_xor(s1, 16);
    s1 += __shfl_xor(s1, 32);

    if (g == 0) {
      const int base = (b << 12) + (i << 6) + (jh << 5);
      out[base + c]      = 1.f / (1.f + __expf(-(s0 + bias3)));
      out[base + 16 + c] = 1.f / (1.f + __expf(-(s1 + bias3)));
    }
  }
}

extern "C" void kernel_launch(void* const* d_in, const int* in_sizes, int n_in,
                              void* d_out, int out_size, void* d_ws,
                              size_t ws_size, hipStream_t stream)
{
  const float* af = (const float*)d_in[0];   // (128,64,128)
  const float* W1 = (const float*)d_in[1];   // (128,128)
  const float* b1 = (const float*)d_in[2];   // (128,)
  const float* W2 = (const float*)d_in[3];   // (128,128)
  const float* b2 = (const float*)d_in[4];   // (128,)
  const float* w3 = (const float*)d_in[5];   // (128,)
  const float* b3 = (const float*)d_in[6];   // (1,)
  const float* mw = (const float*)d_in[7];   // (64,)
  float* out = (float*)d_out;                // 524288 corr + 64 weights

  float* AiP = (float*)d_ws;                           // 4 MB
  float* Aj  = AiP + B_SZ * N_SZ * H_SZ;               // 4 MB
  unsigned short* W2T = (unsigned short*)(Aj + B_SZ * N_SZ * H_SZ);  // 32 KB
  float* tab = (float*)(W2T + H_SZ * H_SZ);            // 2 KB

  setup_kernel<<<2114, 256, 0, stream>>>(af, W1, b1, W2, mw, b2, w3,
                                         AiP, Aj, W2T, tab,
                                         out + B_SZ * N_SZ * N_SZ);
  // 1024 blocks x 8 waves; block = (b, 8 i's); 2 independent strips/wave
  corr_kernel<<<1024, 512, 0, stream>>>(AiP, Aj, W2T, tab, b3, out);
}